// Round 1
// baseline (260.925 us; speedup 1.0000x reference)
//
#include <hip/hip_runtime.h>
#include <hip/hip_bf16.h>

// difficultyWeightedLoss: mean over N of  w(t) * CE(logits[i], t[i]),  C=2.
// CE = logsumexp(l0,l1) - l_t = softplus(l_other - l_target).
// w = 1.4 if t==0 else 1.0.  text_keys (d_in[2]) is unused by the reference.
//
// Memory-bound: 134 MB logits + 67 MB targets read, 4 B out.
// Two-kernel deterministic reduction: partials (float, per block) in d_ws,
// final double-accumulated mean in d_out.

#define NBLK 2048
#define NTHR 256

__global__ __launch_bounds__(NTHR) void dwl_partial_kernel(
    const float* __restrict__ logits,   // (N,2) row-major
    const int* __restrict__ targets,    // (N,)
    float* __restrict__ partials,       // (NBLK,)
    int n)
{
    const int tid    = blockIdx.x * NTHR + threadIdx.x;
    const int stride = gridDim.x * NTHR;

    const float4* lg4 = reinterpret_cast<const float4*>(logits);
    const int4*   tg4 = reinterpret_cast<const int4*>(targets);
    const int nQuads = n >> 2;   // 4 samples per iteration per thread

    float acc = 0.0f;

    for (int q = tid; q < nQuads; q += stride) {
        // two float4 = samples {4q,4q+1} and {4q+2,4q+3}; 32 B/lane contiguous
        const float4 a = lg4[2 * q];
        const float4 b = lg4[2 * q + 1];
        const int4   t = tg4[q];

        float l0[4] = {a.x, a.z, b.x, b.z};
        float l1[4] = {a.y, a.w, b.y, b.w};
        int   tt[4] = {t.x, t.y, t.z, t.w};

        #pragma unroll
        for (int k = 0; k < 4; ++k) {
            const bool one = (tt[k] == 1);
            const float lt = one ? l1[k] : l0[k];
            const float lo = one ? l0[k] : l1[k];
            const float d  = lo - lt;
            // stable softplus(d) = max(d,0) + log1p(exp(-|d|))
            const float ce = fmaxf(d, 0.0f) + __logf(1.0f + __expf(-fabsf(d)));
            const float w  = one ? 1.0f : 1.4f;
            acc += ce * w;
        }
    }

    // wave64 shuffle reduction
    #pragma unroll
    for (int off = 32; off > 0; off >>= 1)
        acc += __shfl_down(acc, off);

    __shared__ float smem[NTHR / 64];
    const int lane = threadIdx.x & 63;
    const int wave = threadIdx.x >> 6;
    if (lane == 0) smem[wave] = acc;
    __syncthreads();

    if (threadIdx.x == 0) {
        float blockSum = 0.0f;
        #pragma unroll
        for (int wv = 0; wv < NTHR / 64; ++wv) blockSum += smem[wv];
        partials[blockIdx.x] = blockSum;
    }
}

__global__ __launch_bounds__(NTHR) void dwl_final_kernel(
    const float* __restrict__ partials,  // (NBLK,)
    float* __restrict__ out,
    float invN)
{
    double acc = 0.0;
    for (int i = threadIdx.x; i < NBLK; i += NTHR)
        acc += (double)partials[i];

    #pragma unroll
    for (int off = 32; off > 0; off >>= 1)
        acc += __shfl_down(acc, off);

    __shared__ double smem[NTHR / 64];
    const int lane = threadIdx.x & 63;
    const int wave = threadIdx.x >> 6;
    if (lane == 0) smem[wave] = acc;
    __syncthreads();

    if (threadIdx.x == 0) {
        double s = 0.0;
        #pragma unroll
        for (int wv = 0; wv < NTHR / 64; ++wv) s += smem[wv];
        out[0] = (float)(s * (double)invN);
    }
}

extern "C" void kernel_launch(void* const* d_in, const int* in_sizes, int n_in,
                              void* d_out, int out_size, void* d_ws, size_t ws_size,
                              hipStream_t stream) {
    const float* logits  = (const float*)d_in[0];
    const int*   targets = (const int*)d_in[1];
    // d_in[2] (text_keys) unused by the reference — do not read it.

    const int n = in_sizes[1];           // N samples (in_sizes[0] == 2*N)
    float* partials = (float*)d_ws;      // NBLK floats = 8 KiB, well under ws_size
    float* out = (float*)d_out;

    dwl_partial_kernel<<<NBLK, NTHR, 0, stream>>>(logits, targets, partials, n);
    dwl_final_kernel<<<1, NTHR, 0, stream>>>(partials, out, 1.0f / (double)n);
}